// Round 10
// baseline (309.140 us; speedup 1.0000x reference)
//
#include <hip/hip_runtime.h>

#define LOG2E 1.44269504088896340736f

typedef __attribute__((ext_vector_type(4)))  float  f32x4;
typedef __attribute__((ext_vector_type(16))) float  f32x16;
typedef __attribute__((ext_vector_type(8)))  __bf16 bf16x8;
typedef __attribute__((ext_vector_type(4)))  __bf16 bf16x4;

static __device__ __forceinline__ f32x4 mfma16(bf16x8 a, bf16x8 b, f32x4 c) {
  return __builtin_amdgcn_mfma_f32_16x16x32_bf16(a, b, c, 0, 0, 0);
}
static __device__ __forceinline__ f32x16 mfma32(bf16x8 a, bf16x8 b, f32x16 c) {
  return __builtin_amdgcn_mfma_f32_32x32x16_bf16(a, b, c, 0, 0, 0);
}

// B=8, L=4096, C=256, C8=32 hardcoded.

// ---------------- fp32 -> bf16 conversion (vectorized) ----------------
__global__ void cvt_f32_to_bf16(const float* __restrict__ s, __bf16* __restrict__ d, int n4) {
  const int stride = gridDim.x * blockDim.x;
  for (int i = blockIdx.x * blockDim.x + threadIdx.x; i < n4; i += stride) {
    const float4 v = reinterpret_cast<const float4*>(s)[i];
    bf16x4 o = { (__bf16)v.x, (__bf16)v.y, (__bf16)v.z, (__bf16)v.w };
    reinterpret_cast<bf16x4*>(d)[i] = o;
  }
}

// all three weight matrices in one launch
__global__ __launch_bounds__(256) void cvt_weights(
    const float* __restrict__ wq, const float* __restrict__ wk, const float* __restrict__ wv,
    __bf16* __restrict__ dq, __bf16* __restrict__ dk, __bf16* __restrict__ dv) {
  const int i = blockIdx.x * 256 + threadIdx.x;
  const float* s; __bf16* d; int off;
  if (i < 2048)      { s = wq; d = dq; off = i; }
  else if (i < 4096) { s = wk; d = dk; off = i - 2048; }
  else               { s = wv; d = dv; off = i - 4096; }
  const float4 v = reinterpret_cast<const float4*>(s)[off];
  bf16x4 o = { (__bf16)v.x, (__bf16)v.y, (__bf16)v.z, (__bf16)v.w };
  reinterpret_cast<bf16x4*>(d)[off] = o;
}

// ---------------- Q/K projection: split-bf16 out, Q pre-scaled by LOG2E ----------------
__global__ __launch_bounds__(256) void qk_proj(
    const __bf16* __restrict__ x, const __bf16* __restrict__ wq, const __bf16* __restrict__ wk,
    const float* __restrict__ bq, const float* __restrict__ bk,
    __bf16* __restrict__ Qh, __bf16* __restrict__ Ql,
    __bf16* __restrict__ Kh, __bf16* __restrict__ Kl)
{
  const int w = threadIdx.x >> 6, lane = threadIdx.x & 63;
  const int lo = lane & 15, hi = lane >> 4;
  const int m0 = blockIdx.x * 64 + w * 16;
  f32x4 acc[4] = {};
  for (int ks = 0; ks < 8; ++ks) {
    const bf16x8 a = *reinterpret_cast<const bf16x8*>(x + (size_t)(m0 + lo) * 256 + ks * 32 + hi * 8);
    #pragma unroll
    for (int nt = 0; nt < 4; ++nt) {
      const int d = nt * 16 + lo;
      const __bf16* wrow = (nt < 2) ? (wq + d * 256) : (wk + (d - 32) * 256);
      const bf16x8 bfr = *reinterpret_cast<const bf16x8*>(wrow + ks * 32 + hi * 8);
      acc[nt] = mfma16(a, bfr, acc[nt]);
    }
  }
  #pragma unroll
  for (int nt = 0; nt < 4; ++nt) {
    const int d = nt * 16 + lo;
    const float bias = (nt < 2) ? bq[d] : bk[d - 32];
    #pragma unroll
    for (int r = 0; r < 4; ++r) {
      const size_t row = m0 + hi * 4 + r;
      float v = acc[nt][r] + bias;
      if (nt < 2) v *= LOG2E;          // fold log2(e) into Q
      const __bf16 vh = (__bf16)v;
      const __bf16 vl = (__bf16)(v - (float)vh);
      if (nt < 2) { Qh[row * 32 + d] = vh;        Ql[row * 32 + d] = vl; }
      else        { Kh[row * 32 + (d - 32)] = vh; Kl[row * 32 + (d - 32)] = vl; }
    }
  }
}

// ---------------- V projection, output TRANSPOSED: VT[b][c][l] ----------------
__global__ __launch_bounds__(256) void v_proj(
    const __bf16* __restrict__ x, const __bf16* __restrict__ wv, const float* __restrict__ bv,
    __bf16* __restrict__ VT)
{
  const int w = threadIdx.x >> 6, lane = threadIdx.x & 63;
  const int lo = lane & 15, hi = lane >> 4;
  const int bn = blockIdx.x & 511, bc = blockIdx.x >> 9;
  const int n0 = bn * 64;
  const int c0 = bc * 64 + w * 16;
  f32x4 acc[4] = {};
  for (int ks = 0; ks < 8; ++ks) {
    const bf16x8 a = *reinterpret_cast<const bf16x8*>(wv + (size_t)(c0 + lo) * 256 + ks * 32 + hi * 8);
    #pragma unroll
    for (int nt = 0; nt < 4; ++nt) {
      const bf16x8 bfr = *reinterpret_cast<const bf16x8*>(x + (size_t)(n0 + nt * 16 + lo) * 256 + ks * 32 + hi * 8);
      acc[nt] = mfma16(bfr, a, acc[nt]);   // A=x rows(n), B=wv cols(c)
    }
  }
  const int bb = n0 >> 12;
  const int c = c0 + lo;
  const float bias = bv[c];
  #pragma unroll
  for (int nt = 0; nt < 4; ++nt) {
    const int n = (n0 + nt * 16 + hi * 4) & 4095;
    bf16x4 pk = { (__bf16)(acc[nt][0] + bias), (__bf16)(acc[nt][1] + bias),
                  (__bf16)(acc[nt][2] + bias), (__bf16)(acc[nt][3] + bias) };
    *reinterpret_cast<bf16x4*>(VT + (size_t)(bb * 256 + c) * 4096 + n) = pk;
  }
}

// ---------------- fused flash attention + reshape + residual ----------------
// 512 threads / 8 waves, TQ=64. QK: 16 (qt,jt) tiles, 2 per wave (qt=w&3,
// jtp=w>>2) -- no duplication; lane-local fixed-base softmax. P: ONE shared
// dbuf [64q][64j] (the only cross-wave resource; 1 barrier/iter, pipelined:
// iter t does PV(t-1)+QK(t)). PV: wave w owns c-slice [32w,+32) for ALL 64q;
// each V 16B frag feeds 2 mfma32 (qg=0/1); V bytes read once per block. V
// regions are WAVE-PRIVATE (stage own 4KB via global_load_lds pre-swizzled,
// read own) -- no barrier needed for V, only counted intra-wave vmcnt.
// R9 fix: stage swizzle must use LOCAL row (r_l ^ g), matching the read
// swizzle (rule 21: same involution on both sides) -- R8 used the global
// row block (w*4+g), scrambling V j-slots for odd waves.
__global__ __launch_bounds__(512, 4) void attn_kernel(
    const __bf16* __restrict__ Qhi, const __bf16* __restrict__ Qlo,
    const __bf16* __restrict__ Khi, const __bf16* __restrict__ Klo,
    const __bf16* __restrict__ VT,
    const float* __restrict__ feats, const float* __restrict__ gptr,
    float* __restrict__ out)
{
  __shared__ alignas(16) __bf16 vlds[2][8][2048];  // per-wave [32c][64j], swz
  __shared__ alignas(16) __bf16 pbuf[2][4096];     // shared P [64q][64j], swz

  const int tid = threadIdx.x;
  const int w   = tid >> 6, lane = tid & 63;
  const int lo  = lane & 15, hi = lane >> 4;
  const int l31 = lane & 31, h  = lane >> 5;
  const int qt  = w & 3, jtp = w >> 2;
  const int b    = blockIdx.x & 7;                 // batch -> XCD affinity
  const int qblk = (blockIdx.x >> 3) * 64;

  // Q B-frag for the wave's single q-tile
  const int qi = (b * 4096 + qblk + qt * 16 + lo) * 32 + hi * 8;
  const bf16x8 qh = *reinterpret_cast<const bf16x8*>(Qhi + qi);
  const bf16x8 ql = *reinterpret_cast<const bf16x8*>(Qlo + qi);

  // K rows: j = jb + jtp*32 + jj*16 + lo  (elem offset kbase + jb*32 + jj*512)
  const int kbase = (b * 4096 + jtp * 32 + lo) * 32 + hi * 8;

  // V stage sources (pre-swizzled): instr g, lane covers r_l=lane>>3, s_l=lane&7
  // local row r_loc = g*8 + r_l  ->  swizzle (r_l ^ g) & 7  (MATCHES read)
  const int r_l = lane >> 3, s_l = lane & 7;
  const __bf16* vsrc[4];
  #pragma unroll
  for (int g = 0; g < 4; ++g) {
    const int row = w * 32 + g * 8 + r_l;           // c-row within batch slice
    const int sw  = s_l ^ ((r_l ^ g) & 7);
    vsrc[g] = VT + (size_t)(b * 256 + row) * 4096 + sw * 8;
  }

  // P write coords: q = qt*16+lo
  const int q   = qt * 16 + lo;
  const int swq = (q ^ (q >> 3)) & 7;
  // P read coords: q' = qg*32 + l31
  int swp[2], prow[2];
  #pragma unroll
  for (int qg = 0; qg < 2; ++qg) {
    const int qq = qg * 32 + l31;
    prow[qg] = qq * 128;
    swp[qg]  = (qq ^ (qq >> 3)) & 7;
  }
  // V read coords
  const int vrow = l31 * 128;
  const int swv  = (l31 ^ (l31 >> 3)) & 7;

  f32x16 o0 = {}, o1 = {};
  f32x4  lacc = {};

  #define STAGE_V(JB, BUF)                                                        \
    { _Pragma("unroll")                                                           \
      for (int g = 0; g < 4; ++g) {                                               \
        __builtin_amdgcn_global_load_lds(                                         \
            (const __attribute__((address_space(1))) void*)(vsrc[g] + (JB)),      \
            (__attribute__((address_space(3))) void*)(&vlds[BUF][w][g * 512 + lane * 8]), \
            16, 0, 0);                                                            \
      } }

  #define PV_STEP(PRV)                                                            \
    { const char* const pr = (const char*)&pbuf[PRV][0];                          \
      const char* const vr = (const char*)&vlds[PRV][w][0] + vrow;                \
      bf16x8 pa0[4], pa1[4], vf[4];                                               \
      _Pragma("unroll")                                                           \
      for (int ks = 0; ks < 4; ++ks) {                                            \
        pa0[ks] = *reinterpret_cast<const bf16x8*>(pr + prow[0] + ((((ks * 2 + h) ^ swp[0])) << 4)); \
        pa1[ks] = *reinterpret_cast<const bf16x8*>(pr + prow[1] + ((((ks * 2 + h) ^ swp[1])) << 4)); \
        vf[ks]  = *reinterpret_cast<const bf16x8*>(vr + ((((ks * 2 + h) ^ swv)) << 4)); \
      }                                                                           \
      __builtin_amdgcn_s_setprio(1);                                              \
      _Pragma("unroll")                                                           \
      for (int ks = 0; ks < 4; ++ks) {                                            \
        o0 = mfma32(pa0[ks], vf[ks], o0);                                         \
        o1 = mfma32(pa1[ks], vf[ks], o1);                                         \
      }                                                                           \
      __builtin_amdgcn_s_setprio(0); }

  // ---- prologue / peeled t=0 ----
  {
    // issue K(0) first (oldest), then stage V(0)
    const bf16x8 kh0 = *reinterpret_cast<const bf16x8*>(Khi + kbase);
    const bf16x8 kl0 = *reinterpret_cast<const bf16x8*>(Klo + kbase);
    const bf16x8 kh1 = *reinterpret_cast<const bf16x8*>(Khi + kbase + 512);
    const bf16x8 kl1 = *reinterpret_cast<const bf16x8*>(Klo + kbase + 512);
    STAGE_V(0, 0);
    __builtin_amdgcn_sched_barrier(0);
    // QK(0) + softmax + P(0) write (compiler waits on kh/kl use)
    #pragma unroll
    for (int jj = 0; jj < 2; ++jj) {
      const bf16x8 kh_ = jj ? kh1 : kh0;
      const bf16x8 kl_ = jj ? kl1 : kl0;
      f32x4 s_ = {0.f, 0.f, 0.f, 0.f};
      s_ = mfma16(kh_, qh, s_);
      s_ = mfma16(kl_, qh, s_);
      s_ = mfma16(kh_, ql, s_);
      f32x4 p4;
      #pragma unroll
      for (int r = 0; r < 4; ++r) p4[r] = __builtin_amdgcn_exp2f(s_[r]);
      lacc += p4;
      bf16x4 pk = { (__bf16)p4[0], (__bf16)p4[1], (__bf16)p4[2], (__bf16)p4[3] };
      const int slot = ((jtp * 2 + jj) * 2 + (hi >> 1)) ^ swq;
      *reinterpret_cast<bf16x4*>((char*)&pbuf[0][0] + q * 128 + (slot << 4) + ((hi & 1) << 3)) = pk;
    }
    asm volatile("s_waitcnt lgkmcnt(0)" ::: "memory");
    __builtin_amdgcn_sched_barrier(0);
    __builtin_amdgcn_s_barrier();
  }

  // ---- main loop t=1..63: PV(t-1) + QK(t) ----
  #pragma unroll 2
  for (int t = 1; t < 64; ++t) {
    const int jb  = t * 64;
    const int cur = t & 1, prv = cur ^ 1;

    asm volatile("s_waitcnt vmcnt(0)" ::: "memory");   // stage V(t-1) landed
    __builtin_amdgcn_sched_barrier(0);

    // issue K(t) (oldest 4), then stage V(t) into buf cur
    const bf16x8 kh0 = *reinterpret_cast<const bf16x8*>(Khi + kbase + jb * 32);
    const bf16x8 kl0 = *reinterpret_cast<const bf16x8*>(Klo + kbase + jb * 32);
    const bf16x8 kh1 = *reinterpret_cast<const bf16x8*>(Khi + kbase + jb * 32 + 512);
    const bf16x8 kl1 = *reinterpret_cast<const bf16x8*>(Klo + kbase + jb * 32 + 512);
    STAGE_V(jb, cur);
    __builtin_amdgcn_sched_barrier(0);

    // PV(t-1) from prv buffers (P visible via barrier, V own-wave staged)
    PV_STEP(prv);

    asm volatile("s_waitcnt vmcnt(4)" ::: "memory");   // K(t) done; stage flying
    __builtin_amdgcn_sched_barrier(0);

    // QK(t) + softmax + P(t) write into cur
    #pragma unroll
    for (int jj = 0; jj < 2; ++jj) {
      const bf16x8 kh_ = jj ? kh1 : kh0;
      const bf16x8 kl_ = jj ? kl1 : kl0;
      f32x4 s_ = {0.f, 0.f, 0.f, 0.f};
      s_ = mfma16(kh_, qh, s_);
      s_ = mfma16(kl_, qh, s_);
      s_ = mfma16(kh_, ql, s_);
      f32x4 p4;
      #pragma unroll
      for (int r = 0; r < 4; ++r) p4[r] = __builtin_amdgcn_exp2f(s_[r]);
      lacc += p4;
      bf16x4 pk = { (__bf16)p4[0], (__bf16)p4[1], (__bf16)p4[2], (__bf16)p4[3] };
      const int slot = ((jtp * 2 + jj) * 2 + (hi >> 1)) ^ swq;
      *reinterpret_cast<bf16x4*>((char*)&pbuf[cur][0] + q * 128 + (slot << 4) + ((hi & 1) << 3)) = pk;
    }

    asm volatile("s_waitcnt lgkmcnt(0)" ::: "memory");
    __builtin_amdgcn_sched_barrier(0);
    __builtin_amdgcn_s_barrier();
    asm volatile("" ::: "memory");
  }

  // ---- drain: PV(63) (buffers index 1) ----
  asm volatile("s_waitcnt vmcnt(0)" ::: "memory");
  __builtin_amdgcn_sched_barrier(0);
  PV_STEP(1);

  #undef STAGE_V
  #undef PV_STEP

  // ---- l reduction: lane-local -> cross-hi -> cross-jtp via LDS ----
  float la = lacc[0] + lacc[1] + lacc[2] + lacc[3];
  la += __shfl_xor(la, 16);
  la += __shfl_xor(la, 32);
  float* const lp = (float*)&pbuf[0][0];     // reuse P buf 0 (drain read buf 1)
  __syncthreads();                           // all PV(63) reads of pbuf done
  if (lane < 16) lp[jtp * 64 + qt * 16 + lo] = la;
  __syncthreads();

  // ---- epilogue: y[b, c*4096+q] = gamma*O[q][c]/l + x ----
  const float g = gptr[0];
  const int c = w * 32 + l31;
  const size_t obase = (size_t)b * (256 * 4096) + (size_t)c * 4096 + qblk;
  #pragma unroll
  for (int qg = 0; qg < 2; ++qg) {
    const f32x16& o_ = qg ? o1 : o0;
    #pragma unroll
    for (int grp = 0; grp < 4; ++grp) {
      const int q0 = qg * 32 + grp * 8 + 4 * h;
      const f32x4 lv0 = *reinterpret_cast<const f32x4*>(&lp[q0]);
      const f32x4 lv1 = *reinterpret_cast<const f32x4*>(&lp[64 + q0]);
      const size_t idx = obase + q0;
      const float4 xr = *reinterpret_cast<const float4*>(feats + idx);
      float4 y;
      y.x = o_[grp * 4 + 0] * (g / (lv0[0] + lv1[0])) + xr.x;
      y.y = o_[grp * 4 + 1] * (g / (lv0[1] + lv1[1])) + xr.y;
      y.z = o_[grp * 4 + 2] * (g / (lv0[2] + lv1[2])) + xr.z;
      y.w = o_[grp * 4 + 3] * (g / (lv0[3] + lv1[3])) + xr.w;
      *reinterpret_cast<float4*>(out + idx) = y;
    }
  }
}

extern "C" void kernel_launch(void* const* d_in, const int* in_sizes, int n_in,
                              void* d_out, int out_size, void* d_ws, size_t ws_size,
                              hipStream_t stream) {
  const float* feats = (const float*)d_in[0];
  const float* Wq    = (const float*)d_in[1];
  const float* bq    = (const float*)d_in[2];
  const float* Wk    = (const float*)d_in[3];
  const float* bk    = (const float*)d_in[4];
  const float* Wv    = (const float*)d_in[5];
  const float* bv    = (const float*)d_in[6];
  const float* gamma = (const float*)d_in[7];
  float* out = (float*)d_out;

  // workspace layout (bytes)
  char* ws = (char*)d_ws;
  const size_t SZ_X  = 16777216;           // x bf16 [32768][256]
  const size_t SZ_QK = 2097152;            // each of Qh/Ql/Kh/Kl [32768][32]
  const size_t SZ_VT = 16777216;           // VT bf16 [8][256][4096]
  const size_t NEED = SZ_X + 4 * SZ_QK + SZ_VT + 2 * 16384 + 131072;
  if (ws_size < NEED) return;

  __bf16* xb  = (__bf16*)(ws);
  __bf16* Qh  = (__bf16*)(ws + SZ_X);
  __bf16* Ql  = (__bf16*)(ws + SZ_X + SZ_QK);
  __bf16* Kh  = (__bf16*)(ws + SZ_X + 2 * SZ_QK);
  __bf16* Kl  = (__bf16*)(ws + SZ_X + 3 * SZ_QK);
  __bf16* VT  = (__bf16*)(ws + SZ_X + 4 * SZ_QK);
  __bf16* wqb = (__bf16*)(ws + SZ_X + 4 * SZ_QK + SZ_VT);
  __bf16* wkb = wqb + 32 * 256;
  __bf16* wvb = wkb + 32 * 256;

  cvt_f32_to_bf16<<<2048, 256, 0, stream>>>(feats, xb, 8388608 / 4);
  cvt_weights<<<80, 256, 0, stream>>>(Wq, Wk, Wv, wqb, wkb, wvb);

  qk_proj<<<512, 256, 0, stream>>>(xb, wqb, wkb, bq, bk, Qh, Ql, Kh, Kl);
  v_proj <<<2048, 256, 0, stream>>>(xb, wvb, bv, VT);
  attn_kernel<<<512, 512, 0, stream>>>(Qh, Ql, Kh, Kl, VT, feats, gamma, out);
}

// Round 11
// 237.237 us; speedup vs baseline: 1.3031x; 1.3031x over previous
//
#include <hip/hip_runtime.h>

#define LOG2E 1.44269504088896340736f

typedef __attribute__((ext_vector_type(4)))  float  f32x4;
typedef __attribute__((ext_vector_type(16))) float  f32x16;
typedef __attribute__((ext_vector_type(8)))  __bf16 bf16x8;
typedef __attribute__((ext_vector_type(4)))  __bf16 bf16x4;

static __device__ __forceinline__ f32x4 mfma16(bf16x8 a, bf16x8 b, f32x4 c) {
  return __builtin_amdgcn_mfma_f32_16x16x32_bf16(a, b, c, 0, 0, 0);
}
static __device__ __forceinline__ f32x16 mfma32(bf16x8 a, bf16x8 b, f32x16 c) {
  return __builtin_amdgcn_mfma_f32_32x32x16_bf16(a, b, c, 0, 0, 0);
}

// B=8, L=4096, C=256, C8=32 hardcoded.

// ---------------- fp32 -> bf16 conversion (vectorized) ----------------
__global__ void cvt_f32_to_bf16(const float* __restrict__ s, __bf16* __restrict__ d, int n4) {
  const int stride = gridDim.x * blockDim.x;
  for (int i = blockIdx.x * blockDim.x + threadIdx.x; i < n4; i += stride) {
    const float4 v = reinterpret_cast<const float4*>(s)[i];
    bf16x4 o = { (__bf16)v.x, (__bf16)v.y, (__bf16)v.z, (__bf16)v.w };
    reinterpret_cast<bf16x4*>(d)[i] = o;
  }
}

// all three weight matrices in one launch
__global__ __launch_bounds__(256) void cvt_weights(
    const float* __restrict__ wq, const float* __restrict__ wk, const float* __restrict__ wv,
    __bf16* __restrict__ dq, __bf16* __restrict__ dk, __bf16* __restrict__ dv) {
  const int i = blockIdx.x * 256 + threadIdx.x;
  const float* s; __bf16* d; int off;
  if (i < 2048)      { s = wq; d = dq; off = i; }
  else if (i < 4096) { s = wk; d = dk; off = i - 2048; }
  else               { s = wv; d = dv; off = i - 4096; }
  const float4 v = reinterpret_cast<const float4*>(s)[off];
  bf16x4 o = { (__bf16)v.x, (__bf16)v.y, (__bf16)v.z, (__bf16)v.w };
  reinterpret_cast<bf16x4*>(d)[off] = o;
}

// ---------------- Q/K projection: split-bf16 out, Q pre-scaled by LOG2E ----------------
__global__ __launch_bounds__(256) void qk_proj(
    const __bf16* __restrict__ x, const __bf16* __restrict__ wq, const __bf16* __restrict__ wk,
    const float* __restrict__ bq, const float* __restrict__ bk,
    __bf16* __restrict__ Qh, __bf16* __restrict__ Ql,
    __bf16* __restrict__ Kh, __bf16* __restrict__ Kl)
{
  const int w = threadIdx.x >> 6, lane = threadIdx.x & 63;
  const int lo = lane & 15, hi = lane >> 4;
  const int m0 = blockIdx.x * 64 + w * 16;
  f32x4 acc[4] = {};
  for (int ks = 0; ks < 8; ++ks) {
    const bf16x8 a = *reinterpret_cast<const bf16x8*>(x + (size_t)(m0 + lo) * 256 + ks * 32 + hi * 8);
    #pragma unroll
    for (int nt = 0; nt < 4; ++nt) {
      const int d = nt * 16 + lo;
      const __bf16* wrow = (nt < 2) ? (wq + d * 256) : (wk + (d - 32) * 256);
      const bf16x8 bfr = *reinterpret_cast<const bf16x8*>(wrow + ks * 32 + hi * 8);
      acc[nt] = mfma16(a, bfr, acc[nt]);
    }
  }
  #pragma unroll
  for (int nt = 0; nt < 4; ++nt) {
    const int d = nt * 16 + lo;
    const float bias = (nt < 2) ? bq[d] : bk[d - 32];
    #pragma unroll
    for (int r = 0; r < 4; ++r) {
      const size_t row = m0 + hi * 4 + r;
      float v = acc[nt][r] + bias;
      if (nt < 2) v *= LOG2E;          // fold log2(e) into Q
      const __bf16 vh = (__bf16)v;
      const __bf16 vl = (__bf16)(v - (float)vh);
      if (nt < 2) { Qh[row * 32 + d] = vh;        Ql[row * 32 + d] = vl; }
      else        { Kh[row * 32 + (d - 32)] = vh; Kl[row * 32 + (d - 32)] = vl; }
    }
  }
}

// ---------------- V projection, output TRANSPOSED: VT[b][c][l] ----------------
__global__ __launch_bounds__(256) void v_proj(
    const __bf16* __restrict__ x, const __bf16* __restrict__ wv, const float* __restrict__ bv,
    __bf16* __restrict__ VT)
{
  const int w = threadIdx.x >> 6, lane = threadIdx.x & 63;
  const int lo = lane & 15, hi = lane >> 4;
  const int bn = blockIdx.x & 511, bc = blockIdx.x >> 9;
  const int n0 = bn * 64;
  const int c0 = bc * 64 + w * 16;
  f32x4 acc[4] = {};
  for (int ks = 0; ks < 8; ++ks) {
    const bf16x8 a = *reinterpret_cast<const bf16x8*>(wv + (size_t)(c0 + lo) * 256 + ks * 32 + hi * 8);
    #pragma unroll
    for (int nt = 0; nt < 4; ++nt) {
      const bf16x8 bfr = *reinterpret_cast<const bf16x8*>(x + (size_t)(n0 + nt * 16 + lo) * 256 + ks * 32 + hi * 8);
      acc[nt] = mfma16(bfr, a, acc[nt]);   // A=x rows(n), B=wv cols(c)
    }
  }
  const int bb = n0 >> 12;
  const int c = c0 + lo;
  const float bias = bv[c];
  #pragma unroll
  for (int nt = 0; nt < 4; ++nt) {
    const int n = (n0 + nt * 16 + hi * 4) & 4095;
    bf16x4 pk = { (__bf16)(acc[nt][0] + bias), (__bf16)(acc[nt][1] + bias),
                  (__bf16)(acc[nt][2] + bias), (__bf16)(acc[nt][3] + bias) };
    *reinterpret_cast<bf16x4*>(VT + (size_t)(bb * 256 + c) * 4096 + n) = pk;
  }
}

// ---------------- fused flash attention + reshape + residual ----------------
// 512 threads / 8 waves, TQ=64. QK: 16 (qt,jt) tiles, 2 per wave (qt=w&3,
// jtp=w>>2) -- no duplication; lane-local fixed-base softmax. P: ONE shared
// dbuf [64q][64j] (the only cross-wave resource; 1 barrier/iter, pipelined:
// iter t does PV(t-1)+QK(t)). PV: wave w owns c-slice [32w,+32) for ALL 64q;
// each V 16B frag feeds 2 mfma32 (qg=0/1); V bytes read once per block. V
// regions are WAVE-PRIVATE (stage own 4KB via global_load_lds pre-swizzled,
// read own) -- no barrier needed for V, only counted intra-wave vmcnt.
// R10 fix: launch_bounds min-occupancy hint 4 -> 2. R9's (512,4) made the
// compiler target the 64-VGPR tier: the ~110-reg live set spilled ~470MB/
// dispatch to scratch (FETCH 260MB, WRITE 248MB). (512,2) caps at the
// 128-VGPR tier; compiler's natural ~112 fits -> 4 waves/SIMD, no spills.
__global__ __launch_bounds__(512, 2) void attn_kernel(
    const __bf16* __restrict__ Qhi, const __bf16* __restrict__ Qlo,
    const __bf16* __restrict__ Khi, const __bf16* __restrict__ Klo,
    const __bf16* __restrict__ VT,
    const float* __restrict__ feats, const float* __restrict__ gptr,
    float* __restrict__ out)
{
  __shared__ alignas(16) __bf16 vlds[2][8][2048];  // per-wave [32c][64j], swz
  __shared__ alignas(16) __bf16 pbuf[2][4096];     // shared P [64q][64j], swz

  const int tid = threadIdx.x;
  const int w   = tid >> 6, lane = tid & 63;
  const int lo  = lane & 15, hi = lane >> 4;
  const int l31 = lane & 31, h  = lane >> 5;
  const int qt  = w & 3, jtp = w >> 2;
  const int b    = blockIdx.x & 7;                 // batch -> XCD affinity
  const int qblk = (blockIdx.x >> 3) * 64;

  // Q B-frag for the wave's single q-tile
  const int qi = (b * 4096 + qblk + qt * 16 + lo) * 32 + hi * 8;
  const bf16x8 qh = *reinterpret_cast<const bf16x8*>(Qhi + qi);
  const bf16x8 ql = *reinterpret_cast<const bf16x8*>(Qlo + qi);

  // K rows: j = jb + jtp*32 + jj*16 + lo  (elem offset kbase + jb*32 + jj*512)
  const int kbase = (b * 4096 + jtp * 32 + lo) * 32 + hi * 8;

  // V stage sources (pre-swizzled): instr g, lane covers r_l=lane>>3, s_l=lane&7
  // local row r_loc = g*8 + r_l  ->  swizzle (r_l ^ g) & 7  (MATCHES read)
  const int r_l = lane >> 3, s_l = lane & 7;
  const __bf16* vsrc[4];
  #pragma unroll
  for (int g = 0; g < 4; ++g) {
    const int row = w * 32 + g * 8 + r_l;           // c-row within batch slice
    const int sw  = s_l ^ ((r_l ^ g) & 7);
    vsrc[g] = VT + (size_t)(b * 256 + row) * 4096 + sw * 8;
  }

  // P write coords: q = qt*16+lo
  const int q   = qt * 16 + lo;
  const int swq = (q ^ (q >> 3)) & 7;
  // P read coords: q' = qg*32 + l31
  int swp[2], prow[2];
  #pragma unroll
  for (int qg = 0; qg < 2; ++qg) {
    const int qq = qg * 32 + l31;
    prow[qg] = qq * 128;
    swp[qg]  = (qq ^ (qq >> 3)) & 7;
  }
  // V read coords
  const int vrow = l31 * 128;
  const int swv  = (l31 ^ (l31 >> 3)) & 7;

  f32x16 o0 = {}, o1 = {};
  f32x4  lacc = {};

  #define STAGE_V(JB, BUF)                                                        \
    { _Pragma("unroll")                                                           \
      for (int g = 0; g < 4; ++g) {                                               \
        __builtin_amdgcn_global_load_lds(                                         \
            (const __attribute__((address_space(1))) void*)(vsrc[g] + (JB)),      \
            (__attribute__((address_space(3))) void*)(&vlds[BUF][w][g * 512 + lane * 8]), \
            16, 0, 0);                                                            \
      } }

  #define PV_STEP(PRV)                                                            \
    { const char* const pr = (const char*)&pbuf[PRV][0];                          \
      const char* const vr = (const char*)&vlds[PRV][w][0] + vrow;                \
      bf16x8 pa0[4], pa1[4], vf[4];                                               \
      _Pragma("unroll")                                                           \
      for (int ks = 0; ks < 4; ++ks) {                                            \
        pa0[ks] = *reinterpret_cast<const bf16x8*>(pr + prow[0] + ((((ks * 2 + h) ^ swp[0])) << 4)); \
        pa1[ks] = *reinterpret_cast<const bf16x8*>(pr + prow[1] + ((((ks * 2 + h) ^ swp[1])) << 4)); \
        vf[ks]  = *reinterpret_cast<const bf16x8*>(vr + ((((ks * 2 + h) ^ swv)) << 4)); \
      }                                                                           \
      __builtin_amdgcn_s_setprio(1);                                              \
      _Pragma("unroll")                                                           \
      for (int ks = 0; ks < 4; ++ks) {                                            \
        o0 = mfma32(pa0[ks], vf[ks], o0);                                         \
        o1 = mfma32(pa1[ks], vf[ks], o1);                                         \
      }                                                                           \
      __builtin_amdgcn_s_setprio(0); }

  // ---- prologue / peeled t=0 ----
  {
    // issue K(0) first (oldest), then stage V(0)
    const bf16x8 kh0 = *reinterpret_cast<const bf16x8*>(Khi + kbase);
    const bf16x8 kl0 = *reinterpret_cast<const bf16x8*>(Klo + kbase);
    const bf16x8 kh1 = *reinterpret_cast<const bf16x8*>(Khi + kbase + 512);
    const bf16x8 kl1 = *reinterpret_cast<const bf16x8*>(Klo + kbase + 512);
    STAGE_V(0, 0);
    __builtin_amdgcn_sched_barrier(0);
    // QK(0) + softmax + P(0) write (compiler waits on kh/kl use)
    #pragma unroll
    for (int jj = 0; jj < 2; ++jj) {
      const bf16x8 kh_ = jj ? kh1 : kh0;
      const bf16x8 kl_ = jj ? kl1 : kl0;
      f32x4 s_ = {0.f, 0.f, 0.f, 0.f};
      s_ = mfma16(kh_, qh, s_);
      s_ = mfma16(kl_, qh, s_);
      s_ = mfma16(kh_, ql, s_);
      f32x4 p4;
      #pragma unroll
      for (int r = 0; r < 4; ++r) p4[r] = __builtin_amdgcn_exp2f(s_[r]);
      lacc += p4;
      bf16x4 pk = { (__bf16)p4[0], (__bf16)p4[1], (__bf16)p4[2], (__bf16)p4[3] };
      const int slot = ((jtp * 2 + jj) * 2 + (hi >> 1)) ^ swq;
      *reinterpret_cast<bf16x4*>((char*)&pbuf[0][0] + q * 128 + (slot << 4) + ((hi & 1) << 3)) = pk;
    }
    asm volatile("s_waitcnt lgkmcnt(0)" ::: "memory");
    __builtin_amdgcn_sched_barrier(0);
    __builtin_amdgcn_s_barrier();
  }

  // ---- main loop t=1..63: PV(t-1) + QK(t) ----
  #pragma unroll 2
  for (int t = 1; t < 64; ++t) {
    const int jb  = t * 64;
    const int cur = t & 1, prv = cur ^ 1;

    asm volatile("s_waitcnt vmcnt(0)" ::: "memory");   // stage V(t-1) landed
    __builtin_amdgcn_sched_barrier(0);

    // issue K(t) (oldest 4), then stage V(t) into buf cur
    const bf16x8 kh0 = *reinterpret_cast<const bf16x8*>(Khi + kbase + jb * 32);
    const bf16x8 kl0 = *reinterpret_cast<const bf16x8*>(Klo + kbase + jb * 32);
    const bf16x8 kh1 = *reinterpret_cast<const bf16x8*>(Khi + kbase + jb * 32 + 512);
    const bf16x8 kl1 = *reinterpret_cast<const bf16x8*>(Klo + kbase + jb * 32 + 512);
    STAGE_V(jb, cur);
    __builtin_amdgcn_sched_barrier(0);

    // PV(t-1) from prv buffers (P visible via barrier, V own-wave staged)
    PV_STEP(prv);

    asm volatile("s_waitcnt vmcnt(4)" ::: "memory");   // K(t) done; stage flying
    __builtin_amdgcn_sched_barrier(0);

    // QK(t) + softmax + P(t) write into cur
    #pragma unroll
    for (int jj = 0; jj < 2; ++jj) {
      const bf16x8 kh_ = jj ? kh1 : kh0;
      const bf16x8 kl_ = jj ? kl1 : kl0;
      f32x4 s_ = {0.f, 0.f, 0.f, 0.f};
      s_ = mfma16(kh_, qh, s_);
      s_ = mfma16(kl_, qh, s_);
      s_ = mfma16(kh_, ql, s_);
      f32x4 p4;
      #pragma unroll
      for (int r = 0; r < 4; ++r) p4[r] = __builtin_amdgcn_exp2f(s_[r]);
      lacc += p4;
      bf16x4 pk = { (__bf16)p4[0], (__bf16)p4[1], (__bf16)p4[2], (__bf16)p4[3] };
      const int slot = ((jtp * 2 + jj) * 2 + (hi >> 1)) ^ swq;
      *reinterpret_cast<bf16x4*>((char*)&pbuf[cur][0] + q * 128 + (slot << 4) + ((hi & 1) << 3)) = pk;
    }

    asm volatile("s_waitcnt lgkmcnt(0)" ::: "memory");
    __builtin_amdgcn_sched_barrier(0);
    __builtin_amdgcn_s_barrier();
    asm volatile("" ::: "memory");
  }

  // ---- drain: PV(63) (buffers index 1) ----
  asm volatile("s_waitcnt vmcnt(0)" ::: "memory");
  __builtin_amdgcn_sched_barrier(0);
  PV_STEP(1);

  #undef STAGE_V
  #undef PV_STEP

  // ---- l reduction: lane-local -> cross-hi -> cross-jtp via LDS ----
  float la = lacc[0] + lacc[1] + lacc[2] + lacc[3];
  la += __shfl_xor(la, 16);
  la += __shfl_xor(la, 32);
  float* const lp = (float*)&pbuf[0][0];     // reuse P buf 0 (drain read buf 1)
  __syncthreads();                           // all PV(63) reads of pbuf done
  if (lane < 16) lp[jtp * 64 + qt * 16 + lo] = la;
  __syncthreads();

  // ---- epilogue: y[b, c*4096+q] = gamma*O[q][c]/l + x ----
  const float g = gptr[0];
  const int c = w * 32 + l31;
  const size_t obase = (size_t)b * (256 * 4096) + (size_t)c * 4096 + qblk;
  #pragma unroll
  for (int qg = 0; qg < 2; ++qg) {
    const f32x16& o_ = qg ? o1 : o0;
    #pragma unroll
    for (int grp = 0; grp < 4; ++grp) {
      const int q0 = qg * 32 + grp * 8 + 4 * h;
      const f32x4 lv0 = *reinterpret_cast<const f32x4*>(&lp[q0]);
      const f32x4 lv1 = *reinterpret_cast<const f32x4*>(&lp[64 + q0]);
      const size_t idx = obase + q0;
      const float4 xr = *reinterpret_cast<const float4*>(feats + idx);
      float4 y;
      y.x = o_[grp * 4 + 0] * (g / (lv0[0] + lv1[0])) + xr.x;
      y.y = o_[grp * 4 + 1] * (g / (lv0[1] + lv1[1])) + xr.y;
      y.z = o_[grp * 4 + 2] * (g / (lv0[2] + lv1[2])) + xr.z;
      y.w = o_[grp * 4 + 3] * (g / (lv0[3] + lv1[3])) + xr.w;
      *reinterpret_cast<float4*>(out + idx) = y;
    }
  }
}

extern "C" void kernel_launch(void* const* d_in, const int* in_sizes, int n_in,
                              void* d_out, int out_size, void* d_ws, size_t ws_size,
                              hipStream_t stream) {
  const float* feats = (const float*)d_in[0];
  const float* Wq    = (const float*)d_in[1];
  const float* bq    = (const float*)d_in[2];
  const float* Wk    = (const float*)d_in[3];
  const float* bk    = (const float*)d_in[4];
  const float* Wv    = (const float*)d_in[5];
  const float* bv    = (const float*)d_in[6];
  const float* gamma = (const float*)d_in[7];
  float* out = (float*)d_out;

  // workspace layout (bytes)
  char* ws = (char*)d_ws;
  const size_t SZ_X  = 16777216;           // x bf16 [32768][256]
  const size_t SZ_QK = 2097152;            // each of Qh/Ql/Kh/Kl [32768][32]
  const size_t SZ_VT = 16777216;           // VT bf16 [8][256][4096]
  const size_t NEED = SZ_X + 4 * SZ_QK + SZ_VT + 2 * 16384 + 131072;
  if (ws_size < NEED) return;

  __bf16* xb  = (__bf16*)(ws);
  __bf16* Qh  = (__bf16*)(ws + SZ_X);
  __bf16* Ql  = (__bf16*)(ws + SZ_X + SZ_QK);
  __bf16* Kh  = (__bf16*)(ws + SZ_X + 2 * SZ_QK);
  __bf16* Kl  = (__bf16*)(ws + SZ_X + 3 * SZ_QK);
  __bf16* VT  = (__bf16*)(ws + SZ_X + 4 * SZ_QK);
  __bf16* wqb = (__bf16*)(ws + SZ_X + 4 * SZ_QK + SZ_VT);
  __bf16* wkb = wqb + 32 * 256;
  __bf16* wvb = wkb + 32 * 256;

  cvt_f32_to_bf16<<<2048, 256, 0, stream>>>(feats, xb, 8388608 / 4);
  cvt_weights<<<80, 256, 0, stream>>>(Wq, Wk, Wv, wqb, wkb, wvb);

  qk_proj<<<512, 256, 0, stream>>>(xb, wqb, wkb, bq, bk, Qh, Ql, Kh, Kl);
  v_proj <<<2048, 256, 0, stream>>>(xb, wvb, bv, VT);
  attn_kernel<<<512, 512, 0, stream>>>(Qh, Ql, Kh, Kl, VT, feats, gamma, out);
}

// Round 12
// 191.786 us; speedup vs baseline: 1.6119x; 1.2370x over previous
//
#include <hip/hip_runtime.h>

#define LOG2E 1.44269504088896340736f

typedef __attribute__((ext_vector_type(4)))  float  f32x4;
typedef __attribute__((ext_vector_type(16))) float  f32x16;
typedef __attribute__((ext_vector_type(8)))  __bf16 bf16x8;
typedef __attribute__((ext_vector_type(4)))  __bf16 bf16x4;

static __device__ __forceinline__ f32x4 mfma16(bf16x8 a, bf16x8 b, f32x4 c) {
  return __builtin_amdgcn_mfma_f32_16x16x32_bf16(a, b, c, 0, 0, 0);
}
static __device__ __forceinline__ f32x16 mfma32(bf16x8 a, bf16x8 b, f32x16 c) {
  return __builtin_amdgcn_mfma_f32_32x32x16_bf16(a, b, c, 0, 0, 0);
}

// B=8, L=4096, C=256, C8=32 hardcoded.

// ---------------- fp32 -> bf16 conversion (vectorized) ----------------
__global__ void cvt_f32_to_bf16(const float* __restrict__ s, __bf16* __restrict__ d, int n4) {
  const int stride = gridDim.x * blockDim.x;
  for (int i = blockIdx.x * blockDim.x + threadIdx.x; i < n4; i += stride) {
    const float4 v = reinterpret_cast<const float4*>(s)[i];
    bf16x4 o = { (__bf16)v.x, (__bf16)v.y, (__bf16)v.z, (__bf16)v.w };
    reinterpret_cast<bf16x4*>(d)[i] = o;
  }
}

// all three weight matrices in one launch
__global__ __launch_bounds__(256) void cvt_weights(
    const float* __restrict__ wq, const float* __restrict__ wk, const float* __restrict__ wv,
    __bf16* __restrict__ dq, __bf16* __restrict__ dk, __bf16* __restrict__ dv) {
  const int i = blockIdx.x * 256 + threadIdx.x;
  const float* s; __bf16* d; int off;
  if (i < 2048)      { s = wq; d = dq; off = i; }
  else if (i < 4096) { s = wk; d = dk; off = i - 2048; }
  else               { s = wv; d = dv; off = i - 4096; }
  const float4 v = reinterpret_cast<const float4*>(s)[off];
  bf16x4 o = { (__bf16)v.x, (__bf16)v.y, (__bf16)v.z, (__bf16)v.w };
  reinterpret_cast<bf16x4*>(d)[off] = o;
}

// ---------------- Q/K projection: split-bf16 out, Q pre-scaled by LOG2E ----------------
__global__ __launch_bounds__(256) void qk_proj(
    const __bf16* __restrict__ x, const __bf16* __restrict__ wq, const __bf16* __restrict__ wk,
    const float* __restrict__ bq, const float* __restrict__ bk,
    __bf16* __restrict__ Qh, __bf16* __restrict__ Ql,
    __bf16* __restrict__ Kh, __bf16* __restrict__ Kl)
{
  const int w = threadIdx.x >> 6, lane = threadIdx.x & 63;
  const int lo = lane & 15, hi = lane >> 4;
  const int m0 = blockIdx.x * 64 + w * 16;
  f32x4 acc[4] = {};
  for (int ks = 0; ks < 8; ++ks) {
    const bf16x8 a = *reinterpret_cast<const bf16x8*>(x + (size_t)(m0 + lo) * 256 + ks * 32 + hi * 8);
    #pragma unroll
    for (int nt = 0; nt < 4; ++nt) {
      const int d = nt * 16 + lo;
      const __bf16* wrow = (nt < 2) ? (wq + d * 256) : (wk + (d - 32) * 256);
      const bf16x8 bfr = *reinterpret_cast<const bf16x8*>(wrow + ks * 32 + hi * 8);
      acc[nt] = mfma16(a, bfr, acc[nt]);
    }
  }
  #pragma unroll
  for (int nt = 0; nt < 4; ++nt) {
    const int d = nt * 16 + lo;
    const float bias = (nt < 2) ? bq[d] : bk[d - 32];
    #pragma unroll
    for (int r = 0; r < 4; ++r) {
      const size_t row = m0 + hi * 4 + r;
      float v = acc[nt][r] + bias;
      if (nt < 2) v *= LOG2E;          // fold log2(e) into Q
      const __bf16 vh = (__bf16)v;
      const __bf16 vl = (__bf16)(v - (float)vh);
      if (nt < 2) { Qh[row * 32 + d] = vh;        Ql[row * 32 + d] = vl; }
      else        { Kh[row * 32 + (d - 32)] = vh; Kl[row * 32 + (d - 32)] = vl; }
    }
  }
}

// ---------------- V projection, output TRANSPOSED: VT[b][c][l] ----------------
__global__ __launch_bounds__(256) void v_proj(
    const __bf16* __restrict__ x, const __bf16* __restrict__ wv, const float* __restrict__ bv,
    __bf16* __restrict__ VT)
{
  const int w = threadIdx.x >> 6, lane = threadIdx.x & 63;
  const int lo = lane & 15, hi = lane >> 4;
  const int bn = blockIdx.x & 511, bc = blockIdx.x >> 9;
  const int n0 = bn * 64;
  const int c0 = bc * 64 + w * 16;
  f32x4 acc[4] = {};
  for (int ks = 0; ks < 8; ++ks) {
    const bf16x8 a = *reinterpret_cast<const bf16x8*>(wv + (size_t)(c0 + lo) * 256 + ks * 32 + hi * 8);
    #pragma unroll
    for (int nt = 0; nt < 4; ++nt) {
      const bf16x8 bfr = *reinterpret_cast<const bf16x8*>(x + (size_t)(n0 + nt * 16 + lo) * 256 + ks * 32 + hi * 8);
      acc[nt] = mfma16(bfr, a, acc[nt]);   // A=x rows(n), B=wv cols(c)
    }
  }
  const int bb = n0 >> 12;
  const int c = c0 + lo;
  const float bias = bv[c];
  #pragma unroll
  for (int nt = 0; nt < 4; ++nt) {
    const int n = (n0 + nt * 16 + hi * 4) & 4095;
    bf16x4 pk = { (__bf16)(acc[nt][0] + bias), (__bf16)(acc[nt][1] + bias),
                  (__bf16)(acc[nt][2] + bias), (__bf16)(acc[nt][3] + bias) };
    *reinterpret_cast<bf16x4*>(VT + (size_t)(bb * 256 + c) * 4096 + n) = pk;
  }
}

// ---------------- fused flash attention + reshape + residual ----------------
// 512 threads / 8 waves, TQ=64, TK=32 (128 iters). QK: 8 (qt,jt) tiles, 1 per
// wave (qt=w&3, jt=w>>2), lane-local fixed-base softmax, 3 mfma16. P: shared
// dbuf [64q][128B rows] (16KB), 1 barrier/iter, pipelined PV(t-1)+QK(t). PV:
// wave w owns c-slice [32w,+32) for all 64q, 4 mfma32; V per wave [32c][32j]
// 64B rows, wave-private, staged via global_load_lds (pre-swizzled source).
// Sync: vmcnt(2) (drains K(t), keeps newest V-stage flying), lgkmcnt(0)
// BEFORE stage-issue (V dbuf WAR safety, wave-private), one raw s_barrier.
// LDS 48KB, no launch-bounds min hint -> natural VGPR, 2 blocks/CU target.
__global__ __launch_bounds__(512) void attn_kernel(
    const __bf16* __restrict__ Qhi, const __bf16* __restrict__ Qlo,
    const __bf16* __restrict__ Khi, const __bf16* __restrict__ Klo,
    const __bf16* __restrict__ VT,
    const float* __restrict__ feats, const float* __restrict__ gptr,
    float* __restrict__ out)
{
  __shared__ alignas(16) __bf16 vlds[2][8][1024];  // per-wave [32c][32j], 2KB
  __shared__ alignas(16) __bf16 pbuf[2][4096];     // P [64q][128B rows], 8KB

  const int tid = threadIdx.x;
  const int w   = tid >> 6, lane = tid & 63;
  const int lo  = lane & 15, hi = lane >> 4;
  const int l31 = lane & 31, h  = lane >> 5;
  const int qt  = w & 3, jt = w >> 2;
  const int b    = blockIdx.x & 7;                 // batch -> XCD affinity
  const int qblk = (blockIdx.x >> 3) * 64;

  // Q B-frag (single q-tile per wave)
  const int qi = (b * 4096 + qblk + qt * 16 + lo) * 32 + hi * 8;
  const bf16x8 qh_ = *reinterpret_cast<const bf16x8*>(Qhi + qi);
  const bf16x8 ql_ = *reinterpret_cast<const bf16x8*>(Qlo + qi);

  // K rows: j = t*32 + jt*16 + lo  -> element offset kbase + t*1024
  const int kbase = (b * 4096 + jt * 16 + lo) * 32 + hi * 8;

  // V stage sources (pre-swizzled, rule 21): instr g covers rows g*16+(lane>>2)
  const __bf16* vsrc[2];
  #pragma unroll
  for (int g = 0; g < 2; ++g) {
    const int cl = g * 16 + (lane >> 2);             // local c row
    const int sl = (lane & 3) ^ ((cl >> 1) & 3);     // logical 16B slot
    vsrc[g] = VT + (size_t)(b * 256 + w * 32 + cl) * 4096 + sl * 8;
  }

  // P write: q = qt*16+lo, slot = jt*2+(hi>>1) (0..3), ^swq into 8-slot row
  const int q    = qt * 16 + lo;
  const int swq  = (q ^ (q >> 3)) & 7;
  const int pwby = q * 128 + (((jt * 2 + (hi >> 1)) ^ swq) << 4) + ((hi & 1) << 3);
  // P read: q' = qg*32+l31, slot = ks*2+h
  int prow[2], swp[2];
  #pragma unroll
  for (int qg = 0; qg < 2; ++qg) {
    const int qq = qg * 32 + l31;
    prow[qg] = qq * 128;
    swp[qg]  = (qq ^ (qq >> 3)) & 7;
  }
  // V read: row l31 (64B), slot = ks*2+h (0..3) ^ 2-bit swizzle
  const int vswz = (l31 >> 1) & 3;

  f32x16 o0 = {}, o1 = {};
  f32x4  lacc = {};
  bf16x8 kh[2], kl[2];

  #define STAGE_V(JB, BUF)                                                        \
    { _Pragma("unroll")                                                           \
      for (int g = 0; g < 2; ++g) {                                               \
        __builtin_amdgcn_global_load_lds(                                         \
            (const __attribute__((address_space(1))) void*)(vsrc[g] + (JB)),      \
            (__attribute__((address_space(3))) void*)(&vlds[BUF][w][g * 512 + lane * 8]), \
            16, 0, 0);                                                            \
      } }

  #define QKSM(CUR)                                                               \
    { f32x4 s_ = {0.f, 0.f, 0.f, 0.f};                                            \
      s_ = mfma16(kh[CUR], qh_, s_);                                              \
      s_ = mfma16(kl[CUR], qh_, s_);                                              \
      s_ = mfma16(kh[CUR], ql_, s_);                                              \
      f32x4 p4;                                                                   \
      _Pragma("unroll")                                                           \
      for (int r = 0; r < 4; ++r) p4[r] = __builtin_amdgcn_exp2f(s_[r]);          \
      lacc += p4;                                                                 \
      bf16x4 pk = { (__bf16)p4[0], (__bf16)p4[1], (__bf16)p4[2], (__bf16)p4[3] }; \
      *reinterpret_cast<bf16x4*>((char*)&pbuf[CUR][0] + pwby) = pk; }

  #define PV_READS(PRV)                                                           \
    { const char* const pr = (const char*)&pbuf[PRV][0];                          \
      const char* const vr = (const char*)&vlds[PRV][w][0] + l31 * 64;            \
      _Pragma("unroll")                                                           \
      for (int ks = 0; ks < 2; ++ks) {                                            \
        pa0[ks] = *reinterpret_cast<const bf16x8*>(pr + prow[0] + ((((ks * 2 + h) ^ swp[0])) << 4)); \
        pa1[ks] = *reinterpret_cast<const bf16x8*>(pr + prow[1] + ((((ks * 2 + h) ^ swp[1])) << 4)); \
        vf[ks]  = *reinterpret_cast<const bf16x8*>(vr + ((((ks * 2 + h) ^ vswz)) << 4)); \
      } }

  #define PV_MFMA()                                                               \
    { __builtin_amdgcn_s_setprio(1);                                              \
      _Pragma("unroll")                                                           \
      for (int ks = 0; ks < 2; ++ks) {                                            \
        o0 = mfma32(pa0[ks], vf[ks], o0);                                         \
        o1 = mfma32(pa1[ks], vf[ks], o1);                                         \
      }                                                                           \
      __builtin_amdgcn_s_setprio(0); }

  // ---- prologue: issue K(0) then stage V(0) (no wait; vmcnt(2) in iter 0) ----
  kh[0] = *reinterpret_cast<const bf16x8*>(Khi + kbase);
  kl[0] = *reinterpret_cast<const bf16x8*>(Klo + kbase);
  STAGE_V(0, 0);
  __builtin_amdgcn_sched_barrier(0);

  // ---- peeled iter 0: QK(0) only (no PV) ----
  {
    asm volatile("s_waitcnt vmcnt(2)" ::: "memory");   // K(0) landed
    __builtin_amdgcn_sched_barrier(0);
    QKSM(0)
    asm volatile("s_waitcnt lgkmcnt(0)" ::: "memory"); // P(0) write drained
    __builtin_amdgcn_sched_barrier(0);
    kh[1] = *reinterpret_cast<const bf16x8*>(Khi + kbase + 1024);
    kl[1] = *reinterpret_cast<const bf16x8*>(Klo + kbase + 1024);
    STAGE_V(32, 1);
    __builtin_amdgcn_sched_barrier(0);
    __builtin_amdgcn_s_barrier();
    asm volatile("" ::: "memory");
  }

  // ---- main loop t=1..127: QK(t) + PV(t-1) ----
  #pragma unroll 2
  for (int t = 1; t < 128; ++t) {
    const int cur = t & 1, prv = cur ^ 1;
    const int jn  = ((t + 1) * 32) & 4095;

    asm volatile("s_waitcnt vmcnt(2)" ::: "memory");   // K(t) done; stage flying
    __builtin_amdgcn_sched_barrier(0);

    QKSM(cur)                                          // QK(t)+softmax+P write

    bf16x8 pa0[2], pa1[2], vf[2];
    PV_READS(prv)                                      // P(t-1), V(t-1)

    asm volatile("s_waitcnt lgkmcnt(0)" ::: "memory"); // reads+write retired
    __builtin_amdgcn_sched_barrier(0);

    // issue K(t+1) then stage V(t+1) (into prv buf -- reads drained above)
    kh[prv] = *reinterpret_cast<const bf16x8*>(Khi + kbase + jn * 32);
    kl[prv] = *reinterpret_cast<const bf16x8*>(Klo + kbase + jn * 32);
    STAGE_V(jn, prv);
    __builtin_amdgcn_sched_barrier(0);

    PV_MFMA()

    __builtin_amdgcn_s_barrier();
    asm volatile("" ::: "memory");
    __builtin_amdgcn_sched_barrier(0);
  }

  // ---- drain: PV(127) ----
  {
    asm volatile("s_waitcnt vmcnt(0)" ::: "memory");   // V(127) stage landed
    __builtin_amdgcn_sched_barrier(0);
    bf16x8 pa0[2], pa1[2], vf[2];
    PV_READS(1)
    PV_MFMA()
  }

  #undef STAGE_V
  #undef QKSM
  #undef PV_READS
  #undef PV_MFMA

  // ---- l reduction: lane-local -> cross-hi -> cross-jt via LDS ----
  float la = lacc[0] + lacc[1] + lacc[2] + lacc[3];
  la += __shfl_xor(la, 16);
  la += __shfl_xor(la, 32);
  float* const lp = (float*)&pbuf[0][0];
  __syncthreads();                          // all PV(127) reads of pbuf done
  if (lane < 16) lp[jt * 64 + qt * 16 + lo] = la;
  __syncthreads();

  // ---- epilogue: y[b, c*4096+q] = gamma*O[q][c]/l + x ----
  const float g = gptr[0];
  const int c = w * 32 + l31;
  const size_t obase = (size_t)b * (256 * 4096) + (size_t)c * 4096 + qblk;
  #pragma unroll
  for (int qg = 0; qg < 2; ++qg) {
    const f32x16& o_ = qg ? o1 : o0;
    #pragma unroll
    for (int grp = 0; grp < 4; ++grp) {
      const int q0 = qg * 32 + grp * 8 + 4 * h;
      const f32x4 lv0 = *reinterpret_cast<const f32x4*>(&lp[q0]);
      const f32x4 lv1 = *reinterpret_cast<const f32x4*>(&lp[64 + q0]);
      const size_t idx = obase + q0;
      const float4 xr = *reinterpret_cast<const float4*>(feats + idx);
      float4 y;
      y.x = o_[grp * 4 + 0] * (g / (lv0[0] + lv1[0])) + xr.x;
      y.y = o_[grp * 4 + 1] * (g / (lv0[1] + lv1[1])) + xr.y;
      y.z = o_[grp * 4 + 2] * (g / (lv0[2] + lv1[2])) + xr.z;
      y.w = o_[grp * 4 + 3] * (g / (lv0[3] + lv1[3])) + xr.w;
      *reinterpret_cast<float4*>(out + idx) = y;
    }
  }
}

extern "C" void kernel_launch(void* const* d_in, const int* in_sizes, int n_in,
                              void* d_out, int out_size, void* d_ws, size_t ws_size,
                              hipStream_t stream) {
  const float* feats = (const float*)d_in[0];
  const float* Wq    = (const float*)d_in[1];
  const float* bq    = (const float*)d_in[2];
  const float* Wk    = (const float*)d_in[3];
  const float* bk    = (const float*)d_in[4];
  const float* Wv    = (const float*)d_in[5];
  const float* bv    = (const float*)d_in[6];
  const float* gamma = (const float*)d_in[7];
  float* out = (float*)d_out;

  // workspace layout (bytes)
  char* ws = (char*)d_ws;
  const size_t SZ_X  = 16777216;           // x bf16 [32768][256]
  const size_t SZ_QK = 2097152;            // each of Qh/Ql/Kh/Kl [32768][32]
  const size_t SZ_VT = 16777216;           // VT bf16 [8][256][4096]
  const size_t NEED = SZ_X + 4 * SZ_QK + SZ_VT + 2 * 16384 + 131072;
  if (ws_size < NEED) return;

  __bf16* xb  = (__bf16*)(ws);
  __bf16* Qh  = (__bf16*)(ws + SZ_X);
  __bf16* Ql  = (__bf16*)(ws + SZ_X + SZ_QK);
  __bf16* Kh  = (__bf16*)(ws + SZ_X + 2 * SZ_QK);
  __bf16* Kl  = (__bf16*)(ws + SZ_X + 3 * SZ_QK);
  __bf16* VT  = (__bf16*)(ws + SZ_X + 4 * SZ_QK);
  __bf16* wqb = (__bf16*)(ws + SZ_X + 4 * SZ_QK + SZ_VT);
  __bf16* wkb = wqb + 32 * 256;
  __bf16* wvb = wkb + 32 * 256;

  cvt_f32_to_bf16<<<2048, 256, 0, stream>>>(feats, xb, 8388608 / 4);
  cvt_weights<<<80, 256, 0, stream>>>(Wq, Wk, Wv, wqb, wkb, wvb);

  qk_proj<<<512, 256, 0, stream>>>(xb, wqb, wkb, bq, bk, Qh, Ql, Kh, Kl);
  v_proj <<<2048, 256, 0, stream>>>(xb, wvb, bv, VT);
  attn_kernel<<<512, 512, 0, stream>>>(Qh, Ql, Kh, Kl, VT, feats, gamma, out);
}

// Round 13
// 169.970 us; speedup vs baseline: 1.8188x; 1.1284x over previous
//
#include <hip/hip_runtime.h>

#define LOG2E 1.44269504088896340736f

typedef __attribute__((ext_vector_type(4)))  float  f32x4;
typedef __attribute__((ext_vector_type(16))) float  f32x16;
typedef __attribute__((ext_vector_type(8)))  __bf16 bf16x8;
typedef __attribute__((ext_vector_type(4)))  __bf16 bf16x4;

static __device__ __forceinline__ f32x4 mfma16(bf16x8 a, bf16x8 b, f32x4 c) {
  return __builtin_amdgcn_mfma_f32_16x16x32_bf16(a, b, c, 0, 0, 0);
}
static __device__ __forceinline__ f32x16 mfma32(bf16x8 a, bf16x8 b, f32x16 c) {
  return __builtin_amdgcn_mfma_f32_32x32x16_bf16(a, b, c, 0, 0, 0);
}

// B=8, L=4096, C=256, C8=32 hardcoded.

// ---------------- fp32 -> bf16 conversion (vectorized) ----------------
__global__ void cvt_f32_to_bf16(const float* __restrict__ s, __bf16* __restrict__ d, int n4) {
  const int stride = gridDim.x * blockDim.x;
  for (int i = blockIdx.x * blockDim.x + threadIdx.x; i < n4; i += stride) {
    const float4 v = reinterpret_cast<const float4*>(s)[i];
    bf16x4 o = { (__bf16)v.x, (__bf16)v.y, (__bf16)v.z, (__bf16)v.w };
    reinterpret_cast<bf16x4*>(d)[i] = o;
  }
}

// all three weight matrices in one launch
__global__ __launch_bounds__(256) void cvt_weights(
    const float* __restrict__ wq, const float* __restrict__ wk, const float* __restrict__ wv,
    __bf16* __restrict__ dq, __bf16* __restrict__ dk, __bf16* __restrict__ dv) {
  const int i = blockIdx.x * 256 + threadIdx.x;
  const float* s; __bf16* d; int off;
  if (i < 2048)      { s = wq; d = dq; off = i; }
  else if (i < 4096) { s = wk; d = dk; off = i - 2048; }
  else               { s = wv; d = dv; off = i - 4096; }
  const float4 v = reinterpret_cast<const float4*>(s)[off];
  bf16x4 o = { (__bf16)v.x, (__bf16)v.y, (__bf16)v.z, (__bf16)v.w };
  reinterpret_cast<bf16x4*>(d)[off] = o;
}

// ---------------- Q/K projection: split-bf16 out, Q pre-scaled by LOG2E ----------------
__global__ __launch_bounds__(256) void qk_proj(
    const __bf16* __restrict__ x, const __bf16* __restrict__ wq, const __bf16* __restrict__ wk,
    const float* __restrict__ bq, const float* __restrict__ bk,
    __bf16* __restrict__ Qh, __bf16* __restrict__ Ql,
    __bf16* __restrict__ Kh, __bf16* __restrict__ Kl)
{
  const int w = threadIdx.x >> 6, lane = threadIdx.x & 63;
  const int lo = lane & 15, hi = lane >> 4;
  const int m0 = blockIdx.x * 64 + w * 16;
  f32x4 acc[4] = {};
  for (int ks = 0; ks < 8; ++ks) {
    const bf16x8 a = *reinterpret_cast<const bf16x8*>(x + (size_t)(m0 + lo) * 256 + ks * 32 + hi * 8);
    #pragma unroll
    for (int nt = 0; nt < 4; ++nt) {
      const int d = nt * 16 + lo;
      const __bf16* wrow = (nt < 2) ? (wq + d * 256) : (wk + (d - 32) * 256);
      const bf16x8 bfr = *reinterpret_cast<const bf16x8*>(wrow + ks * 32 + hi * 8);
      acc[nt] = mfma16(a, bfr, acc[nt]);
    }
  }
  #pragma unroll
  for (int nt = 0; nt < 4; ++nt) {
    const int d = nt * 16 + lo;
    const float bias = (nt < 2) ? bq[d] : bk[d - 32];
    #pragma unroll
    for (int r = 0; r < 4; ++r) {
      const size_t row = m0 + hi * 4 + r;
      float v = acc[nt][r] + bias;
      if (nt < 2) v *= LOG2E;          // fold log2(e) into Q
      const __bf16 vh = (__bf16)v;
      const __bf16 vl = (__bf16)(v - (float)vh);
      if (nt < 2) { Qh[row * 32 + d] = vh;        Ql[row * 32 + d] = vl; }
      else        { Kh[row * 32 + (d - 32)] = vh; Kl[row * 32 + (d - 32)] = vl; }
    }
  }
}

// ---------------- V projection, output TRANSPOSED: VT[b][c][l] ----------------
// R12: 512 blocks x (64n x 256c): 4x fewer blocks, same per-block x traffic
// -> x L2 amplification 16x -> 4x. Operand-swapped MFMA for b64 stores.
__global__ __launch_bounds__(256) void v_proj(
    const __bf16* __restrict__ x, const __bf16* __restrict__ wv, const float* __restrict__ bv,
    __bf16* __restrict__ VT)
{
  const int w = threadIdx.x >> 6, lane = threadIdx.x & 63;
  const int lo = lane & 15, hi = lane >> 4;
  const int n0 = blockIdx.x * 64;
  const int bb = n0 >> 12;
  f32x4 acc[4][4] = {};                      // [nt][ct]
  for (int ks = 0; ks < 8; ++ks) {
    bf16x8 xa[4], wa[4];
    #pragma unroll
    for (int nt = 0; nt < 4; ++nt)
      xa[nt] = *reinterpret_cast<const bf16x8*>(x + (size_t)(n0 + nt * 16 + lo) * 256 + ks * 32 + hi * 8);
    #pragma unroll
    for (int ct = 0; ct < 4; ++ct)
      wa[ct] = *reinterpret_cast<const bf16x8*>(wv + (size_t)(w * 64 + ct * 16 + lo) * 256 + ks * 32 + hi * 8);
    #pragma unroll
    for (int nt = 0; nt < 4; ++nt)
      #pragma unroll
      for (int ct = 0; ct < 4; ++ct)
        acc[nt][ct] = mfma16(xa[nt], wa[ct], acc[nt][ct]);   // A=x rows(n), B=wv cols(c)
  }
  #pragma unroll
  for (int ct = 0; ct < 4; ++ct) {
    const int c = w * 64 + ct * 16 + lo;
    const float bias = bv[c];
    #pragma unroll
    for (int nt = 0; nt < 4; ++nt) {
      const int n = (n0 + nt * 16 + hi * 4) & 4095;
      bf16x4 pk = { (__bf16)(acc[nt][ct][0] + bias), (__bf16)(acc[nt][ct][1] + bias),
                    (__bf16)(acc[nt][ct][2] + bias), (__bf16)(acc[nt][ct][3] + bias) };
      *reinterpret_cast<bf16x4*>(VT + (size_t)(bb * 256 + c) * 4096 + n) = pk;
    }
  }
}

// ---------------- fused flash attention + reshape + residual ----------------
// R11 structure (8 waves, TQ=64, TK=32, 1 barrier/iter, wave-private V stage,
// shared P dbuf, pipelined QK(t)+PV(t-1)) with two fixes:
//  - V LDS layout: 2 c-rows packed per 128B row, full 3-bit XOR swizzle
//    (phys16B = ((c&1)*4+sj) ^ ((c>>1)&7)) -> V reads conflict-free (R11's
//    64B rows gave a structural 4-way conflict = 6.3M cycles).
//  - __launch_bounds__(512,2): empirically (R9/R10/R11) the 2nd arg acts as
//    blocks/CU for 512-thr blocks; 2 -> 128-VGPR cap, no spill.
__global__ __launch_bounds__(512, 2) void attn_kernel(
    const __bf16* __restrict__ Qhi, const __bf16* __restrict__ Qlo,
    const __bf16* __restrict__ Khi, const __bf16* __restrict__ Klo,
    const __bf16* __restrict__ VT,
    const float* __restrict__ feats, const float* __restrict__ gptr,
    float* __restrict__ out)
{
  __shared__ alignas(16) __bf16 vlds[2][8][1024];  // per-wave [16 rows][128B]
  __shared__ alignas(16) __bf16 pbuf[2][4096];     // P [64q][128B rows], 8KB

  const int tid = threadIdx.x;
  const int w   = tid >> 6, lane = tid & 63;
  const int lo  = lane & 15, hi = lane >> 4;
  const int l31 = lane & 31, h  = lane >> 5;
  const int qt  = w & 3, jt = w >> 2;
  const int b    = blockIdx.x & 7;                 // batch -> XCD affinity
  const int qblk = (blockIdx.x >> 3) * 64;

  // Q B-frag (single q-tile per wave)
  const int qi = (b * 4096 + qblk + qt * 16 + lo) * 32 + hi * 8;
  const bf16x8 qh_ = *reinterpret_cast<const bf16x8*>(Qhi + qi);
  const bf16x8 ql_ = *reinterpret_cast<const bf16x8*>(Qlo + qi);

  // K rows: j = t*32 + jt*16 + lo  -> element offset kbase + t*1024
  const int kbase = (b * 4096 + jt * 16 + lo) * 32 + hi * 8;

  // V stage sources (pre-swizzled, rule 21 -- same involution as read):
  // LDS byte g*1024+lane*16 -> row128 = g*8+(lane>>3), phys = lane&7,
  // logical = phys ^ (lane>>3); c_local = 2*row + (logical>>2), j8 = logical&3
  const __bf16* vsrc[2];
  #pragma unroll
  for (int g = 0; g < 2; ++g) {
    const int row = g * 8 + (lane >> 3);
    const int lgc = (lane & 7) ^ (lane >> 3);
    const int cl  = 2 * row + (lgc >> 2);
    vsrc[g] = VT + (size_t)(b * 256 + w * 32 + cl) * 4096 + (lgc & 3) * 8;
  }

  // P write: q = qt*16+lo, slot = jt*2+(hi>>1) (0..3), ^swq into 8-slot row
  const int q    = qt * 16 + lo;
  const int swq  = (q ^ (q >> 3)) & 7;
  const int pwby = q * 128 + (((jt * 2 + (hi >> 1)) ^ swq) << 4) + ((hi & 1) << 3);
  // P read: q' = qg*32+l31, slot = ks*2+h
  int prow[2], swp[2];
  #pragma unroll
  for (int qg = 0; qg < 2; ++qg) {
    const int qq = qg * 32 + l31;
    prow[qg] = qq * 128;
    swp[qg]  = (qq ^ (qq >> 3)) & 7;
  }
  // V read: c = l31 -> row = l31>>1 (128B), logical = (l31&1)*4 + (ks*2+h),
  // phys = logical ^ ((l31>>1)&7)
  const int vrow = (l31 >> 1) * 128;
  const int vlg  = (l31 & 1) * 4;
  const int vxr  = (l31 >> 1) & 7;

  f32x16 o0 = {}, o1 = {};
  f32x4  lacc = {};
  bf16x8 kh[2], kl[2];

  #define STAGE_V(JB, BUF)                                                        \
    { _Pragma("unroll")                                                           \
      for (int g = 0; g < 2; ++g) {                                               \
        __builtin_amdgcn_global_load_lds(                                         \
            (const __attribute__((address_space(1))) void*)(vsrc[g] + (JB)),      \
            (__attribute__((address_space(3))) void*)(&vlds[BUF][w][g * 512 + lane * 8]), \
            16, 0, 0);                                                            \
      } }

  #define QKSM(CUR)                                                               \
    { f32x4 s_ = {0.f, 0.f, 0.f, 0.f};                                            \
      s_ = mfma16(kh[CUR], qh_, s_);                                              \
      s_ = mfma16(kl[CUR], qh_, s_);                                              \
      s_ = mfma16(kh[CUR], ql_, s_);                                              \
      f32x4 p4;                                                                   \
      _Pragma("unroll")                                                           \
      for (int r = 0; r < 4; ++r) p4[r] = __builtin_amdgcn_exp2f(s_[r]);          \
      lacc += p4;                                                                 \
      bf16x4 pk = { (__bf16)p4[0], (__bf16)p4[1], (__bf16)p4[2], (__bf16)p4[3] }; \
      *reinterpret_cast<bf16x4*>((char*)&pbuf[CUR][0] + pwby) = pk; }

  #define PV_READS(PRV)                                                           \
    { const char* const pr = (const char*)&pbuf[PRV][0];                          \
      const char* const vr = (const char*)&vlds[PRV][w][0] + vrow;                \
      _Pragma("unroll")                                                           \
      for (int ks = 0; ks < 2; ++ks) {                                            \
        pa0[ks] = *reinterpret_cast<const bf16x8*>(pr + prow[0] + ((((ks * 2 + h) ^ swp[0])) << 4)); \
        pa1[ks] = *reinterpret_cast<const bf16x8*>(pr + prow[1] + ((((ks * 2 + h) ^ swp[1])) << 4)); \
        vf[ks]  = *reinterpret_cast<const bf16x8*>(vr + ((((vlg + ks * 2 + h) ^ vxr)) << 4)); \
      } }

  #define PV_MFMA()                                                               \
    { __builtin_amdgcn_s_setprio(1);                                              \
      _Pragma("unroll")                                                           \
      for (int ks = 0; ks < 2; ++ks) {                                            \
        o0 = mfma32(pa0[ks], vf[ks], o0);                                         \
        o1 = mfma32(pa1[ks], vf[ks], o1);                                         \
      }                                                                           \
      __builtin_amdgcn_s_setprio(0); }

  // ---- prologue: issue K(0) then stage V(0) (no wait; vmcnt(2) in iter 0) ----
  kh[0] = *reinterpret_cast<const bf16x8*>(Khi + kbase);
  kl[0] = *reinterpret_cast<const bf16x8*>(Klo + kbase);
  STAGE_V(0, 0);
  __builtin_amdgcn_sched_barrier(0);

  // ---- peeled iter 0: QK(0) only (no PV) ----
  {
    asm volatile("s_waitcnt vmcnt(2)" ::: "memory");   // K(0) landed
    __builtin_amdgcn_sched_barrier(0);
    QKSM(0)
    asm volatile("s_waitcnt lgkmcnt(0)" ::: "memory"); // P(0) write drained
    __builtin_amdgcn_sched_barrier(0);
    kh[1] = *reinterpret_cast<const bf16x8*>(Khi + kbase + 1024);
    kl[1] = *reinterpret_cast<const bf16x8*>(Klo + kbase + 1024);
    STAGE_V(32, 1);
    __builtin_amdgcn_sched_barrier(0);
    __builtin_amdgcn_s_barrier();
    asm volatile("" ::: "memory");
  }

  // ---- main loop t=1..127: QK(t) + PV(t-1) ----
  #pragma unroll 2
  for (int t = 1; t < 128; ++t) {
    const int cur = t & 1, prv = cur ^ 1;
    const int jn  = ((t + 1) * 32) & 4095;

    asm volatile("s_waitcnt vmcnt(2)" ::: "memory");   // K(t) done; stage flying
    __builtin_amdgcn_sched_barrier(0);

    QKSM(cur)                                          // QK(t)+softmax+P write

    bf16x8 pa0[2], pa1[2], vf[2];
    PV_READS(prv)                                      // P(t-1), V(t-1)

    asm volatile("s_waitcnt lgkmcnt(0)" ::: "memory"); // reads+write retired
    __builtin_amdgcn_sched_barrier(0);

    // issue K(t+1) then stage V(t+1) (into prv buf -- reads drained above)
    kh[prv] = *reinterpret_cast<const bf16x8*>(Khi + kbase + jn * 32);
    kl[prv] = *reinterpret_cast<const bf16x8*>(Klo + kbase + jn * 32);
    STAGE_V(jn, prv);
    __builtin_amdgcn_sched_barrier(0);

    PV_MFMA()

    __builtin_amdgcn_s_barrier();
    asm volatile("" ::: "memory");
    __builtin_amdgcn_sched_barrier(0);
  }

  // ---- drain: PV(127) ----
  {
    asm volatile("s_waitcnt vmcnt(0)" ::: "memory");   // V(127) stage landed
    __builtin_amdgcn_sched_barrier(0);
    bf16x8 pa0[2], pa1[2], vf[2];
    PV_READS(1)
    PV_MFMA()
  }

  #undef STAGE_V
  #undef QKSM
  #undef PV_READS
  #undef PV_MFMA

  // ---- l reduction: lane-local -> cross-hi -> cross-jt via LDS ----
  float la = lacc[0] + lacc[1] + lacc[2] + lacc[3];
  la += __shfl_xor(la, 16);
  la += __shfl_xor(la, 32);
  float* const lp = (float*)&pbuf[0][0];
  __syncthreads();                          // all PV(127) reads of pbuf done
  if (lane < 16) lp[jt * 64 + qt * 16 + lo] = la;
  __syncthreads();

  // ---- epilogue: y[b, c*4096+q] = gamma*O[q][c]/l + x ----
  const float g = gptr[0];
  const int c = w * 32 + l31;
  const size_t obase = (size_t)b * (256 * 4096) + (size_t)c * 4096 + qblk;
  #pragma unroll
  for (int qg = 0; qg < 2; ++qg) {
    const f32x16& o_ = qg ? o1 : o0;
    #pragma unroll
    for (int grp = 0; grp < 4; ++grp) {
      const int q0 = qg * 32 + grp * 8 + 4 * h;
      const f32x4 lv0 = *reinterpret_cast<const f32x4*>(&lp[q0]);
      const f32x4 lv1 = *reinterpret_cast<const f32x4*>(&lp[64 + q0]);
      const size_t idx = obase + q0;
      const float4 xr = *reinterpret_cast<const float4*>(feats + idx);
      float4 y;
      y.x = o_[grp * 4 + 0] * (g / (lv0[0] + lv1[0])) + xr.x;
      y.y = o_[grp * 4 + 1] * (g / (lv0[1] + lv1[1])) + xr.y;
      y.z = o_[grp * 4 + 2] * (g / (lv0[2] + lv1[2])) + xr.z;
      y.w = o_[grp * 4 + 3] * (g / (lv0[3] + lv1[3])) + xr.w;
      *reinterpret_cast<float4*>(out + idx) = y;
    }
  }
}

extern "C" void kernel_launch(void* const* d_in, const int* in_sizes, int n_in,
                              void* d_out, int out_size, void* d_ws, size_t ws_size,
                              hipStream_t stream) {
  const float* feats = (const float*)d_in[0];
  const float* Wq    = (const float*)d_in[1];
  const float* bq    = (const float*)d_in[2];
  const float* Wk    = (const float*)d_in[3];
  const float* bk    = (const float*)d_in[4];
  const float* Wv    = (const float*)d_in[5];
  const float* bv    = (const float*)d_in[6];
  const float* gamma = (const float*)d_in[7];
  float* out = (float*)d_out;

  // workspace layout (bytes)
  char* ws = (char*)d_ws;
  const size_t SZ_X  = 16777216;           // x bf16 [32768][256]
  const size_t SZ_QK = 2097152;            // each of Qh/Ql/Kh/Kl [32768][32]
  const size_t SZ_VT = 16777216;           // VT bf16 [8][256][4096]
  const size_t NEED = SZ_X + 4 * SZ_QK + SZ_VT + 2 * 16384 + 131072;
  if (ws_size < NEED) return;

  __bf16* xb  = (__bf16*)(ws);
  __bf16* Qh  = (__bf16*)(ws + SZ_X);
  __bf16* Ql  = (__bf16*)(ws + SZ_X + SZ_QK);
  __bf16* Kh  = (__bf16*)(ws + SZ_X + 2 * SZ_QK);
  __bf16* Kl  = (__bf16*)(ws + SZ_X + 3 * SZ_QK);
  __bf16* VT  = (__bf16*)(ws + SZ_X + 4 * SZ_QK);
  __bf16* wqb = (__bf16*)(ws + SZ_X + 4 * SZ_QK + SZ_VT);
  __bf16* wkb = wqb + 32 * 256;
  __bf16* wvb = wkb + 32 * 256;

  cvt_f32_to_bf16<<<2048, 256, 0, stream>>>(feats, xb, 8388608 / 4);
  cvt_weights<<<80, 256, 0, stream>>>(Wq, Wk, Wv, wqb, wkb, wvb);

  qk_proj<<<512, 256, 0, stream>>>(xb, wqb, wkb, bq, bk, Qh, Ql, Kh, Kl);
  v_proj <<<512, 256, 0, stream>>>(xb, wvb, bv, VT);
  attn_kernel<<<512, 512, 0, stream>>>(Qh, Ql, Kh, Kl, VT, feats, gamma, out);
}